// Round 2
// baseline (2123.076 us; speedup 1.0000x reference)
//
#include <hip/hip_runtime.h>

#define NEG_SLOPE 0.2f
#define EPS 1e-6f
#define D_IN 128
#define D_OUT 64

// Fused GEMM: sfeat = X@W1 (optional store), tout = X@W2 (optional store),
// s1 = (X@W1)@a1, s2 = (X@W2)@a2  (per-node score scalars).
// Block: 256 threads, tile 64 rows x 128 cols, K staged in 2 chunks of 64.
__global__ __launch_bounds__(256) void gemm_score(
    const float* __restrict__ X,    // [N][128]
    const float* __restrict__ W1,   // [128][64]
    const float* __restrict__ W2,   // [128][64]
    const float* __restrict__ a1,   // [64]
    const float* __restrict__ a2,   // [64]
    float* __restrict__ sfeat,      // [N][64] or nullptr
    float* __restrict__ tout,       // [N][64] or nullptr
    float* __restrict__ s1,         // [N]
    float* __restrict__ s2,         // [N]
    int N)
{
    __shared__ float Ws[64][128];   // K-chunk of [W1|W2]
    __shared__ float Xs[64][68];    // 64 rows x 64 K (+4 pad)
    const int tid = threadIdx.x;
    const int tx = tid & 15;        // col group: cols tx*8 .. tx*8+7
    const int ty = tid >> 4;        // row group: rows ty*4 .. ty*4+3
    const int br = blockIdx.x * 64;

    float acc[4][8];
    #pragma unroll
    for (int r = 0; r < 4; ++r)
        #pragma unroll
        for (int c = 0; c < 8; ++c) acc[r][c] = 0.f;

    for (int kt = 0; kt < D_IN; kt += 64) {
        // stage W chunk: rows kt..kt+63 of [W1|W2] -> Ws[64][128]
        #pragma unroll
        for (int i = 0; i < 8; ++i) {
            int l = tid + i * 256;          // float4 index 0..2047
            int row = l >> 5;               // 32 float4 per 128-col row
            int c4 = (l & 31) << 2;         // float col
            const float* wsrc = (c4 < 64) ? &W1[(kt + row) * 64 + c4]
                                          : &W2[(kt + row) * 64 + (c4 - 64)];
            *(float4*)&Ws[row][c4] = *(const float4*)wsrc;
        }
        // stage X chunk: rows br..br+63, cols kt..kt+63
        #pragma unroll
        for (int i = 0; i < 4; ++i) {
            int l = tid + i * 256;          // float4 index 0..1023
            int row = l >> 4;               // 16 float4 per 64-col row
            int c4 = (l & 15) << 2;
            float4 v = make_float4(0.f, 0.f, 0.f, 0.f);
            if (br + row < N)
                v = *(const float4*)&X[(size_t)(br + row) * D_IN + kt + c4];
            *(float4*)&Xs[row][c4] = v;
        }
        __syncthreads();
        #pragma unroll 4
        for (int k = 0; k < 64; ++k) {
            float xv[4], wv[8];
            #pragma unroll
            for (int r = 0; r < 4; ++r) xv[r] = Xs[ty * 4 + r][k];
            #pragma unroll
            for (int c = 0; c < 8; ++c) wv[c] = Ws[k][tx * 8 + c];
            #pragma unroll
            for (int r = 0; r < 4; ++r)
                #pragma unroll
                for (int c = 0; c < 8; ++c)
                    acc[r][c] += xv[r] * wv[c];
        }
        __syncthreads();
    }

    // epilogue: cols 0..63 -> sfeat, cols 64..127 -> tout; fused score dot.
    float aa[8];
    const float* av = (tx < 8) ? a1 : a2;
    #pragma unroll
    for (int c = 0; c < 8; ++c) aa[c] = av[(tx & 7) * 8 + c];

    #pragma unroll
    for (int r = 0; r < 4; ++r) {
        int row = br + ty * 4 + r;
        float s = 0.f;
        #pragma unroll
        for (int c = 0; c < 8; ++c) s += acc[r][c] * aa[c];
        // reduce over the 8 lanes sharing this (row, output-half)
        s += __shfl_xor(s, 1);
        s += __shfl_xor(s, 2);
        s += __shfl_xor(s, 4);
        if (row < N) {
            float4 lo = make_float4(acc[r][0], acc[r][1], acc[r][2], acc[r][3]);
            float4 hi = make_float4(acc[r][4], acc[r][5], acc[r][6], acc[r][7]);
            if (tx < 8) {
                if (sfeat) {
                    *(float4*)&sfeat[(size_t)row * 64 + tx * 8]     = lo;
                    *(float4*)&sfeat[(size_t)row * 64 + tx * 8 + 4] = hi;
                }
                if (tx == 0) s1[row] = s;
            } else {
                if (tout) {
                    int cc = (tx - 8) * 8;
                    *(float4*)&tout[(size_t)row * 64 + cc]     = lo;
                    *(float4*)&tout[(size_t)row * 64 + cc + 4] = hi;
                }
                if (tx == 8) s2[row] = s;
            }
        }
    }
}

// Per-edge: att = exp(leakyrelu(s_src[src]+t_tgt[tgt])); atomic scatter of
// att * sfeat[src] into msg[tgt], att into den[tgt]. 16 lanes per edge.
__global__ __launch_bounds__(256) void edge_scatter(
    const int* __restrict__ src, const int* __restrict__ tgt,
    const float* __restrict__ sfeat,  // [Ns][64]
    const float* __restrict__ s1,     // [Ns]
    const float* __restrict__ s2,     // [Nt]
    float* __restrict__ msg,          // [Nt][64]
    float* __restrict__ den,          // [Nt]
    int E)
{
    int t = blockIdx.x * 256 + threadIdx.x;
    int e = t >> 4;
    int lane = t & 15;
    if (e >= E) return;
    int s = src[e];
    int d = tgt[e];
    float sc = s1[s] + s2[d];
    sc = (sc > 0.f) ? sc : NEG_SLOPE * sc;
    float att = expf(sc);
    float4 v = *(const float4*)&sfeat[(size_t)s * 64 + lane * 4];
    float* m = &msg[(size_t)d * 64 + lane * 4];
    atomicAdd(m + 0, v.x * att);
    atomicAdd(m + 1, v.y * att);
    atomicAdd(m + 2, v.z * att);
    atomicAdd(m + 3, v.w * att);
    if (lane == 0) atomicAdd(&den[d], att);
}

// out[n][c] (already holds tx) += msg[n][c] / (den[n] + EPS)
__global__ __launch_bounds__(256) void finalize(
    float* __restrict__ out, const float* __restrict__ msg,
    const float* __restrict__ den, int N)
{
    int t = blockIdx.x * 256 + threadIdx.x;
    if (t >= N * 16) return;
    int n = t >> 4;
    int c4 = (t & 15) << 2;
    float dd = den[n] + EPS;
    float inv = 1.0f / dd;
    float4 m4 = *(const float4*)&msg[(size_t)n * 64 + c4];
    float4 o  = *(const float4*)&out[(size_t)n * 64 + c4];
    o.x += m4.x * inv; o.y += m4.y * inv; o.z += m4.z * inv; o.w += m4.w * inv;
    *(float4*)&out[(size_t)n * 64 + c4] = o;
}

extern "C" void kernel_launch(void* const* d_in, const int* in_sizes, int n_in,
                              void* d_out, int out_size, void* d_ws, size_t ws_size,
                              hipStream_t stream) {
    const float* x_user   = (const float*)d_in[0];
    const float* x_item   = (const float*)d_in[1];
    const float* W_ui_src = (const float*)d_in[2];
    const float* W_ui_tgt = (const float*)d_in[3];
    const float* W_iu_src = (const float*)d_in[4];
    const float* W_iu_tgt = (const float*)d_in[5];
    const float* a_ui     = (const float*)d_in[6];   // [128]
    const float* a_iu     = (const float*)d_in[7];   // [128]
    const int*   edge_ui  = (const int*)d_in[8];     // [2][E]
    const int*   edge_iu  = (const int*)d_in[9];

    const int N_USER = in_sizes[0] / D_IN;
    const int N_ITEM = in_sizes[1] / D_IN;
    const int E_ui = in_sizes[8] / 2;
    const int E_iu = in_sizes[9] / 2;
    const int NMAX = (N_USER > N_ITEM) ? N_USER : N_ITEM;

    float* out = (float*)d_out;
    float* out_user = out;                          // [N_USER][64]
    float* out_item = out + (size_t)N_USER * 64;    // [N_ITEM][64]

    // workspace layout (floats) — sequenced phases share sx_buf and msg/den.
    float* w = (float*)d_ws;
    float* sx_buf    = w;  w += (size_t)NMAX * 64;   // u_sx then i_sx
    float* msg       = w;  w += (size_t)NMAX * 64;   // msg_item then msg_user
    float* den       = w;  w += NMAX;                // den_item then den_user (contiguous after msg)
    float* s_src_ui  = w;  w += N_USER;
    float* t_tgt_iu  = w;  w += N_USER;
    float* s_src_iu  = w;  w += N_ITEM;
    float* t_tgt_ui  = w;  w += N_ITEM;

    size_t need_bytes = (size_t)(w - (float*)d_ws) * sizeof(float);
    if (ws_size < need_bytes) {
        // Workspace too small: launch nothing. Output stays poisoned -> clean
        // failure (diagnosable), instead of an OOB device fault / core dump.
        return;
    }

    size_t msg_den_bytes = ((size_t)NMAX * 64 + NMAX) * sizeof(float);
    int nb_u = (N_USER + 63) / 64;
    int nb_i = (N_ITEM + 63) / 64;

    // 1. user GEMM: u_sx -> sx_buf, tx -> out_user, scores.
    gemm_score<<<nb_u, 256, 0, stream>>>(x_user, W_ui_src, W_iu_tgt,
                                         a_ui, a_iu + 64,
                                         sx_buf, out_user, s_src_ui, t_tgt_iu, N_USER);
    // 2. item GEMM: skip sfeat store (recomputed later), tx -> out_item, scores.
    gemm_score<<<nb_i, 256, 0, stream>>>(x_item, W_iu_src, W_ui_tgt,
                                         a_iu, a_ui + 64,
                                         nullptr, out_item, s_src_iu, t_tgt_ui, N_ITEM);

    // 3. phase A: edges (user -> item), accumulate into msg/den for items.
    hipMemsetAsync(msg, 0, msg_den_bytes, stream);
    {
        int nthreads = E_ui * 16;
        int nb = (nthreads + 255) / 256;
        edge_scatter<<<nb, 256, 0, stream>>>(edge_ui, edge_ui + E_ui,
                                             sx_buf, s_src_ui, t_tgt_ui,
                                             msg, den, E_ui);
    }
    {
        int nb = (N_ITEM * 16 + 255) / 256;
        finalize<<<nb, 256, 0, stream>>>(out_item, msg, den, N_ITEM);
    }

    // 4. recompute item sx into sx_buf (tout skipped: out_item is final).
    gemm_score<<<nb_i, 256, 0, stream>>>(x_item, W_iu_src, W_ui_tgt,
                                         a_iu, a_ui + 64,
                                         sx_buf, nullptr, s_src_iu, t_tgt_ui, N_ITEM);

    // 5. phase B: edges (item -> user), accumulate into msg/den for users.
    hipMemsetAsync(msg, 0, msg_den_bytes, stream);
    {
        int nthreads = E_iu * 16;
        int nb = (nthreads + 255) / 256;
        edge_scatter<<<nb, 256, 0, stream>>>(edge_iu, edge_iu + E_iu,
                                             sx_buf, s_src_iu, t_tgt_iu,
                                             msg, den, E_iu);
    }
    {
        int nb = (N_USER * 16 + 255) / 256;
        finalize<<<nb, 256, 0, stream>>>(out_user, msg, den, N_USER);
    }
}

// Round 4
// 588.611 us; speedup vs baseline: 3.6069x; 3.6069x over previous
//
#include <hip/hip_runtime.h>

#define NEG_SLOPE 0.2f
#define EPS 1e-6f
#define D_IN 128
#define D_OUT 64

// Fused GEMM: sfeat = X@W1 (optional store), tout = X@W2 (optional store),
// s1 = (X@W1)@a1, s2 = (X@W2)@a2  (per-node score scalars).
__global__ __launch_bounds__(256) void gemm_score(
    const float* __restrict__ X,    // [N][128]
    const float* __restrict__ W1,   // [128][64]
    const float* __restrict__ W2,   // [128][64]
    const float* __restrict__ a1,   // [64]
    const float* __restrict__ a2,   // [64]
    float* __restrict__ sfeat,      // [N][64] or nullptr
    float* __restrict__ tout,       // [N][64] or nullptr
    float* __restrict__ s1,         // [N]
    float* __restrict__ s2,         // [N]
    int N)
{
    __shared__ float Ws[64][128];   // K-chunk of [W1|W2]
    __shared__ float Xs[64][68];    // 64 rows x 64 K (+4 pad)
    const int tid = threadIdx.x;
    const int tx = tid & 15;        // col group: cols tx*8 .. tx*8+7
    const int ty = tid >> 4;        // row group: rows ty*4 .. ty*4+3
    const int br = blockIdx.x * 64;

    float acc[4][8];
    #pragma unroll
    for (int r = 0; r < 4; ++r)
        #pragma unroll
        for (int c = 0; c < 8; ++c) acc[r][c] = 0.f;

    for (int kt = 0; kt < D_IN; kt += 64) {
        #pragma unroll
        for (int i = 0; i < 8; ++i) {
            int l = tid + i * 256;
            int row = l >> 5;
            int c4 = (l & 31) << 2;
            const float* wsrc = (c4 < 64) ? &W1[(kt + row) * 64 + c4]
                                          : &W2[(kt + row) * 64 + (c4 - 64)];
            *(float4*)&Ws[row][c4] = *(const float4*)wsrc;
        }
        #pragma unroll
        for (int i = 0; i < 4; ++i) {
            int l = tid + i * 256;
            int row = l >> 4;
            int c4 = (l & 15) << 2;
            float4 v = make_float4(0.f, 0.f, 0.f, 0.f);
            if (br + row < N)
                v = *(const float4*)&X[(size_t)(br + row) * D_IN + kt + c4];
            *(float4*)&Xs[row][c4] = v;
        }
        __syncthreads();
        #pragma unroll 4
        for (int k = 0; k < 64; ++k) {
            float xv[4], wv[8];
            #pragma unroll
            for (int r = 0; r < 4; ++r) xv[r] = Xs[ty * 4 + r][k];
            #pragma unroll
            for (int c = 0; c < 8; ++c) wv[c] = Ws[k][tx * 8 + c];
            #pragma unroll
            for (int r = 0; r < 4; ++r)
                #pragma unroll
                for (int c = 0; c < 8; ++c)
                    acc[r][c] += xv[r] * wv[c];
        }
        __syncthreads();
    }

    float aa[8];
    const float* av = (tx < 8) ? a1 : a2;
    #pragma unroll
    for (int c = 0; c < 8; ++c) aa[c] = av[(tx & 7) * 8 + c];

    #pragma unroll
    for (int r = 0; r < 4; ++r) {
        int row = br + ty * 4 + r;
        float s = 0.f;
        #pragma unroll
        for (int c = 0; c < 8; ++c) s += acc[r][c] * aa[c];
        s += __shfl_xor(s, 1);
        s += __shfl_xor(s, 2);
        s += __shfl_xor(s, 4);
        if (row < N) {
            float4 lo = make_float4(acc[r][0], acc[r][1], acc[r][2], acc[r][3]);
            float4 hi = make_float4(acc[r][4], acc[r][5], acc[r][6], acc[r][7]);
            if (tx < 8) {
                if (sfeat) {
                    *(float4*)&sfeat[(size_t)row * 64 + tx * 8]     = lo;
                    *(float4*)&sfeat[(size_t)row * 64 + tx * 8 + 4] = hi;
                }
                if (tx == 0) s1[row] = s;
            } else {
                if (tout) {
                    int cc = (tx - 8) * 8;
                    *(float4*)&tout[(size_t)row * 64 + cc]     = lo;
                    *(float4*)&tout[(size_t)row * 64 + cc + 4] = hi;
                }
                if (tx == 8) s2[row] = s;
            }
        }
    }
}

__global__ __launch_bounds__(256) void hist_kernel(
    const int* __restrict__ tgt, int* __restrict__ cnt, int E)
{
    int i = blockIdx.x * 256 + threadIdx.x;
    if (i < E) atomicAdd(&cnt[tgt[i]], 1);
}

// exclusive scan, 3-phase. ofs[i] = exclusive-within-block; bsum[b] = block total.
__global__ __launch_bounds__(256) void scan_block(
    const int* __restrict__ cnt, int* __restrict__ ofs, int* __restrict__ bsum, int N)
{
    __shared__ int tmp[256];
    int i = blockIdx.x * 256 + threadIdx.x;
    int v = (i < N) ? cnt[i] : 0;
    tmp[threadIdx.x] = v;
    __syncthreads();
    #pragma unroll
    for (int d = 1; d < 256; d <<= 1) {
        int t = (threadIdx.x >= d) ? tmp[threadIdx.x - d] : 0;
        __syncthreads();
        tmp[threadIdx.x] += t;
        __syncthreads();
    }
    if (i < N) ofs[i] = tmp[threadIdx.x] - v;
    if (threadIdx.x == 255) bsum[blockIdx.x] = tmp[255];
}

__global__ __launch_bounds__(256) void scan_bsums(int* __restrict__ bsum, int nb)
{
    __shared__ int tmp[256];
    __shared__ int carry;
    if (threadIdx.x == 0) carry = 0;
    __syncthreads();
    for (int base = 0; base < nb; base += 256) {
        int i = base + threadIdx.x;
        int v = (i < nb) ? bsum[i] : 0;
        tmp[threadIdx.x] = v;
        __syncthreads();
        #pragma unroll
        for (int d = 1; d < 256; d <<= 1) {
            int t = (threadIdx.x >= d) ? tmp[threadIdx.x - d] : 0;
            __syncthreads();
            tmp[threadIdx.x] += t;
            __syncthreads();
        }
        if (i < nb) bsum[i] = tmp[threadIdx.x] - v + carry;
        __syncthreads();
        if (threadIdx.x == 0) carry += tmp[255];
        __syncthreads();
    }
}

__global__ __launch_bounds__(256) void add_offsets(
    int* __restrict__ ofs, const int* __restrict__ bsum, int N)
{
    int i = blockIdx.x * 256 + threadIdx.x;
    if (i < N) ofs[i] += bsum[blockIdx.x];
}

// Per edge: compute att once, claim slot in CSR via 1 int atomic, store (src, att).
// After this kernel, ofs[t] == end-of-segment (exclusive start + cnt).
__global__ __launch_bounds__(256) void fill_kernel(
    const int* __restrict__ src, const int* __restrict__ tgt,
    const float* __restrict__ s1, const float* __restrict__ s2,
    int* __restrict__ ofs, int2* __restrict__ payload, int E)
{
    int e = blockIdx.x * 256 + threadIdx.x;
    if (e >= E) return;
    int s = src[e];
    int t = tgt[e];
    float sc = s1[s] + s2[t];
    sc = (sc > 0.f) ? sc : NEG_SLOPE * sc;
    float att = expf(sc);
    int pos = atomicAdd(&ofs[t], 1);
    payload[pos] = make_int2(s, __float_as_int(att));
}

// One 64-lane wave per target node; lane l owns feature l.
// out[n][l] (holds tx) += (sum att*sfeat[src][l]) / (sum att + EPS)
__global__ __launch_bounds__(256) void gather_out(
    const int2* __restrict__ payload, const int* __restrict__ ofs,
    const int* __restrict__ cnt, const float* __restrict__ sfeat,
    float* __restrict__ out, int N)
{
    int wid = (blockIdx.x * 256 + threadIdx.x) >> 6;
    int lane = threadIdx.x & 63;
    if (wid >= N) return;
    int end = ofs[wid];
    int deg = cnt[wid];
    int j = end - deg;
    float msg = 0.f, den = 0.f;
    for (; j + 1 < end; j += 2) {
        int2 p0 = payload[j];
        int2 p1 = payload[j + 1];
        float a0 = __int_as_float(p0.y);
        float a1 = __int_as_float(p1.y);
        msg += a0 * sfeat[(size_t)p0.x * 64 + lane];
        msg += a1 * sfeat[(size_t)p1.x * 64 + lane];
        den += a0 + a1;
    }
    if (j < end) {
        int2 p = payload[j];
        float a = __int_as_float(p.y);
        msg += a * sfeat[(size_t)p.x * 64 + lane];
        den += a;
    }
    out[(size_t)wid * 64 + lane] += msg / (den + EPS);
}

extern "C" void kernel_launch(void* const* d_in, const int* in_sizes, int n_in,
                              void* d_out, int out_size, void* d_ws, size_t ws_size,
                              hipStream_t stream) {
    const float* x_user   = (const float*)d_in[0];
    const float* x_item   = (const float*)d_in[1];
    const float* W_ui_src = (const float*)d_in[2];
    const float* W_ui_tgt = (const float*)d_in[3];
    const float* W_iu_src = (const float*)d_in[4];
    const float* W_iu_tgt = (const float*)d_in[5];
    const float* a_ui     = (const float*)d_in[6];   // [128]
    const float* a_iu     = (const float*)d_in[7];   // [128]
    const int*   edge_ui  = (const int*)d_in[8];     // [2][E]
    const int*   edge_iu  = (const int*)d_in[9];

    const int N_USER = in_sizes[0] / D_IN;
    const int N_ITEM = in_sizes[1] / D_IN;
    const int E_ui = in_sizes[8] / 2;
    const int E_iu = in_sizes[9] / 2;
    const int NMAX = (N_USER > N_ITEM) ? N_USER : N_ITEM;
    const int EMAX = (E_ui > E_iu) ? E_ui : E_iu;

    float* out = (float*)d_out;
    float* out_user = out;                          // [N_USER][64]
    float* out_item = out + (size_t)N_USER * 64;    // [N_ITEM][64]

    // ---- workspace layout (floats/ints) ----
    float* w = (float*)d_ws;
    float* sx_u     = w;  w += (size_t)NMAX * 64;
    float* s_src_ui = w;  w += N_USER;
    float* t_tgt_iu = w;  w += N_USER;
    float* s_src_iu = w;  w += N_ITEM;
    float* t_tgt_ui = w;  w += N_ITEM;
    int* cnt  = (int*)w;  w += NMAX;
    int* ofs  = (int*)w;  w += NMAX;
    int nb_scan = (NMAX + 255) / 256;
    int* bsum = (int*)w;  w += (nb_scan + 2) & ~1;   // keep 8B alignment after
    int2* payload = (int2*)w;  w += (size_t)2 * EMAX;

    size_t base_need = (size_t)(w - (float*)d_ws) * sizeof(float);
    if (ws_size < base_need) return;  // clean, diagnosable failure

    // big-ws path: keep item sx too, skip the recompute GEMM
    float* sx_i = nullptr;
    if (ws_size >= base_need + (size_t)NMAX * 64 * sizeof(float)) {
        sx_i = w;
    }

    int nb_u = (N_USER + 63) / 64;
    int nb_i = (N_ITEM + 63) / 64;

    // 1. user GEMM: sx -> sx_u, tx -> out_user, scores s_src_ui / t_tgt_iu
    gemm_score<<<nb_u, 256, 0, stream>>>(x_user, W_ui_src, W_iu_tgt,
                                         a_ui, a_iu + 64,
                                         sx_u, out_user, s_src_ui, t_tgt_iu, N_USER);
    // 2. item GEMM: sx -> sx_i (or skip), tx -> out_item, scores s_src_iu / t_tgt_ui
    gemm_score<<<nb_i, 256, 0, stream>>>(x_item, W_iu_src, W_ui_tgt,
                                         a_iu, a_ui + 64,
                                         sx_i, out_item, s_src_iu, t_tgt_ui, N_ITEM);

    // ---- phase A: edge type ui (user src -> item tgt) ----
    {
        const int* e_src = edge_ui;
        const int* e_tgt = edge_ui + E_ui;
        hipMemsetAsync(cnt, 0, (size_t)N_ITEM * sizeof(int), stream);
        hist_kernel<<<(E_ui + 255) / 256, 256, 0, stream>>>(e_tgt, cnt, E_ui);
        int nb = (N_ITEM + 255) / 256;
        scan_block<<<nb, 256, 0, stream>>>(cnt, ofs, bsum, N_ITEM);
        scan_bsums<<<1, 256, 0, stream>>>(bsum, nb);
        add_offsets<<<nb, 256, 0, stream>>>(ofs, bsum, N_ITEM);
        fill_kernel<<<(E_ui + 255) / 256, 256, 0, stream>>>(
            e_src, e_tgt, s_src_ui, t_tgt_ui, ofs, payload, E_ui);
        gather_out<<<(N_ITEM * 64 + 255) / 256, 256, 0, stream>>>(
            payload, ofs, cnt, sx_u, out_item, N_ITEM);
    }

    // 3. recompute item sx if we couldn't keep it
    const float* sx_phaseB = sx_i;
    if (!sx_i) {
        gemm_score<<<nb_i, 256, 0, stream>>>(x_item, W_iu_src, W_ui_tgt,
                                             a_iu, a_ui + 64,
                                             sx_u, nullptr, s_src_iu, t_tgt_ui, N_ITEM);
        sx_phaseB = sx_u;
    }

    // ---- phase B: edge type iu (item src -> user tgt) ----
    {
        const int* e_src = edge_iu;
        const int* e_tgt = edge_iu + E_iu;
        hipMemsetAsync(cnt, 0, (size_t)N_USER * sizeof(int), stream);
        hist_kernel<<<(E_iu + 255) / 256, 256, 0, stream>>>(e_tgt, cnt, E_iu);
        int nb = (N_USER + 255) / 256;
        scan_block<<<nb, 256, 0, stream>>>(cnt, ofs, bsum, N_USER);
        scan_bsums<<<1, 256, 0, stream>>>(bsum, nb);
        add_offsets<<<nb, 256, 0, stream>>>(ofs, bsum, N_USER);
        fill_kernel<<<(E_iu + 255) / 256, 256, 0, stream>>>(
            e_src, e_tgt, s_src_iu, t_tgt_iu, ofs, payload, E_iu);
        gather_out<<<(N_USER * 64 + 255) / 256, 256, 0, stream>>>(
            payload, ofs, cnt, sx_phaseB, out_user, N_USER);
    }
}

// Round 5
// 513.581 us; speedup vs baseline: 4.1339x; 1.1461x over previous
//
#include <hip/hip_runtime.h>
#include <hip/hip_fp16.h>

#define NEG_SLOPE 0.2f
#define EPS 1e-6f
#define D_IN 128
#define D_OUT 64

// Dual fused GEMM over both node sets in one dispatch.
// Per side: sfeat = half(X@W1), tout = X@W2, s1 = (X@W1)@a1, s2 = (X@W2)@a2.
__global__ __launch_bounds__(256) void gemm_score_dual(
    const float* __restrict__ x_user, const float* __restrict__ x_item,
    const float* __restrict__ W_ui_src, const float* __restrict__ W_ui_tgt,
    const float* __restrict__ W_iu_src, const float* __restrict__ W_iu_tgt,
    const float* __restrict__ a_ui, const float* __restrict__ a_iu,
    __half* __restrict__ sx_u, __half* __restrict__ sx_i,
    float* __restrict__ out_user, float* __restrict__ out_item,
    float* __restrict__ s_src_ui, float* __restrict__ t_tgt_iu,
    float* __restrict__ s_src_iu, float* __restrict__ t_tgt_ui,
    int nb_u, int N_USER, int N_ITEM)
{
    // side selection (wave-uniform)
    const bool is_item = (blockIdx.x >= (unsigned)nb_u);
    const float* X  = is_item ? x_item : x_user;
    const float* W1 = is_item ? W_iu_src : W_ui_src;   // -> sfeat + s1
    const float* W2 = is_item ? W_ui_tgt : W_iu_tgt;   // -> tout + s2
    const float* a1 = is_item ? a_iu : a_ui;           // first half [0:64)
    const float* a2 = is_item ? (a_ui + 64) : (a_iu + 64);
    __half* sfeat   = is_item ? sx_i : sx_u;
    float* tout     = is_item ? out_item : out_user;
    float* s1       = is_item ? s_src_iu : s_src_ui;
    float* s2       = is_item ? t_tgt_ui : t_tgt_iu;
    const int N     = is_item ? N_ITEM : N_USER;
    const int br    = (is_item ? (blockIdx.x - nb_u) : blockIdx.x) * 64;

    __shared__ float Ws[64][128];   // K-chunk of [W1|W2]
    __shared__ float Xs[64][68];    // 64 rows x 64 K (+4 pad)
    const int tid = threadIdx.x;
    const int tx = tid & 15;        // col group: cols tx*8 .. tx*8+7
    const int ty = tid >> 4;        // row group: rows ty*4 .. ty*4+3

    float acc[4][8];
    #pragma unroll
    for (int r = 0; r < 4; ++r)
        #pragma unroll
        for (int c = 0; c < 8; ++c) acc[r][c] = 0.f;

    for (int kt = 0; kt < D_IN; kt += 64) {
        #pragma unroll
        for (int i = 0; i < 8; ++i) {
            int l = tid + i * 256;
            int row = l >> 5;
            int c4 = (l & 31) << 2;
            const float* wsrc = (c4 < 64) ? &W1[(kt + row) * 64 + c4]
                                          : &W2[(kt + row) * 64 + (c4 - 64)];
            *(float4*)&Ws[row][c4] = *(const float4*)wsrc;
        }
        #pragma unroll
        for (int i = 0; i < 4; ++i) {
            int l = tid + i * 256;
            int row = l >> 4;
            int c4 = (l & 15) << 2;
            float4 v = make_float4(0.f, 0.f, 0.f, 0.f);
            if (br + row < N)
                v = *(const float4*)&X[(size_t)(br + row) * D_IN + kt + c4];
            *(float4*)&Xs[row][c4] = v;
        }
        __syncthreads();
        #pragma unroll 4
        for (int k = 0; k < 64; ++k) {
            float xv[4], wv[8];
            #pragma unroll
            for (int r = 0; r < 4; ++r) xv[r] = Xs[ty * 4 + r][k];
            #pragma unroll
            for (int c = 0; c < 8; ++c) wv[c] = Ws[k][tx * 8 + c];
            #pragma unroll
            for (int r = 0; r < 4; ++r)
                #pragma unroll
                for (int c = 0; c < 8; ++c)
                    acc[r][c] += xv[r] * wv[c];
        }
        __syncthreads();
    }

    float aa[8];
    const float* av = (tx < 8) ? a1 : a2;
    #pragma unroll
    for (int c = 0; c < 8; ++c) aa[c] = av[(tx & 7) * 8 + c];

    #pragma unroll
    for (int r = 0; r < 4; ++r) {
        int row = br + ty * 4 + r;
        float s = 0.f;
        #pragma unroll
        for (int c = 0; c < 8; ++c) s += acc[r][c] * aa[c];
        s += __shfl_xor(s, 1);
        s += __shfl_xor(s, 2);
        s += __shfl_xor(s, 4);
        if (row < N) {
            if (tx < 8) {
                union { __half2 h[4]; uint4 u; } pk;
                pk.h[0] = __floats2half2_rn(acc[r][0], acc[r][1]);
                pk.h[1] = __floats2half2_rn(acc[r][2], acc[r][3]);
                pk.h[2] = __floats2half2_rn(acc[r][4], acc[r][5]);
                pk.h[3] = __floats2half2_rn(acc[r][6], acc[r][7]);
                *(uint4*)&sfeat[(size_t)row * 64 + tx * 8] = pk.u;
                if (tx == 0) s1[row] = s;
            } else {
                int cc = (tx - 8) * 8;
                *(float4*)&tout[(size_t)row * 64 + cc] =
                    make_float4(acc[r][0], acc[r][1], acc[r][2], acc[r][3]);
                *(float4*)&tout[(size_t)row * 64 + cc + 4] =
                    make_float4(acc[r][4], acc[r][5], acc[r][6], acc[r][7]);
                if (tx == 8) s2[row] = s;
            }
        }
    }
}

// Combined histogram over both edge types; phase-B targets offset by N_ITEM.
__global__ __launch_bounds__(256) void hist_kernel(
    const int* __restrict__ tgt_a, const int* __restrict__ tgt_b,
    int* __restrict__ cnt, int E_a, int E_b, int N_ITEM)
{
    int i = blockIdx.x * 256 + threadIdx.x;
    if (i < E_a) {
        atomicAdd(&cnt[tgt_a[i]], 1);
    } else if (i < E_a + E_b) {
        atomicAdd(&cnt[tgt_b[i - E_a] + N_ITEM], 1);
    }
}

// exclusive scan, 3-phase
__global__ __launch_bounds__(256) void scan_block(
    const int* __restrict__ cnt, int* __restrict__ ofs, int* __restrict__ bsum, int N)
{
    __shared__ int tmp[256];
    int i = blockIdx.x * 256 + threadIdx.x;
    int v = (i < N) ? cnt[i] : 0;
    tmp[threadIdx.x] = v;
    __syncthreads();
    #pragma unroll
    for (int d = 1; d < 256; d <<= 1) {
        int t = (threadIdx.x >= d) ? tmp[threadIdx.x - d] : 0;
        __syncthreads();
        tmp[threadIdx.x] += t;
        __syncthreads();
    }
    if (i < N) ofs[i] = tmp[threadIdx.x] - v;
    if (threadIdx.x == 255) bsum[blockIdx.x] = tmp[255];
}

__global__ __launch_bounds__(256) void scan_bsums(int* __restrict__ bsum, int nb)
{
    __shared__ int tmp[256];
    __shared__ int carry;
    if (threadIdx.x == 0) carry = 0;
    __syncthreads();
    for (int base = 0; base < nb; base += 256) {
        int i = base + threadIdx.x;
        int v = (i < nb) ? bsum[i] : 0;
        tmp[threadIdx.x] = v;
        __syncthreads();
        #pragma unroll
        for (int d = 1; d < 256; d <<= 1) {
            int t = (threadIdx.x >= d) ? tmp[threadIdx.x - d] : 0;
            __syncthreads();
            tmp[threadIdx.x] += t;
            __syncthreads();
        }
        if (i < nb) bsum[i] = tmp[threadIdx.x] - v + carry;
        __syncthreads();
        if (threadIdx.x == 0) carry += tmp[255];
        __syncthreads();
    }
}

__global__ __launch_bounds__(256) void add_offsets(
    int* __restrict__ ofs, const int* __restrict__ bsum, int N)
{
    int i = blockIdx.x * 256 + threadIdx.x;
    if (i < N) ofs[i] += bsum[blockIdx.x];
}

// Combined fill: compute att once per edge, claim CSR slot, store (src, att).
// After this kernel ofs[t] == end of segment t.
__global__ __launch_bounds__(256) void fill_kernel(
    const int* __restrict__ edge_ui, const int* __restrict__ edge_iu,
    const float* __restrict__ s_src_ui, const float* __restrict__ t_tgt_ui,
    const float* __restrict__ s_src_iu, const float* __restrict__ t_tgt_iu,
    int* __restrict__ ofs, int2* __restrict__ payload,
    int E_a, int E_b, int N_ITEM)
{
    int e = blockIdx.x * 256 + threadIdx.x;
    int s, t, bucket;
    float sc;
    if (e < E_a) {                       // phase A: user -> item
        s = edge_ui[e];
        t = edge_ui[E_a + e];
        sc = s_src_ui[s] + t_tgt_ui[t];
        bucket = t;
    } else if (e < E_a + E_b) {          // phase B: item -> user
        int eb = e - E_a;
        s = edge_iu[eb];
        t = edge_iu[E_b + eb];
        sc = s_src_iu[s] + t_tgt_iu[t];
        bucket = t + N_ITEM;
    } else return;
    sc = (sc > 0.f) ? sc : NEG_SLOPE * sc;
    float att = expf(sc);
    int pos = atomicAdd(&ofs[bucket], 1);
    payload[pos] = make_int2(s, __float_as_int(att));
}

// One 64-lane wave per target node; lane l owns feature l.
// Payload segment is loaded cooperatively (1 coalesced int2 load per 64 edges),
// then each edge is broadcast via shfl -> independent fp16 gathers (MLP).
__global__ __launch_bounds__(256) void gather_out(
    const int2* __restrict__ payload, const int* __restrict__ ofs,
    const int* __restrict__ cnt,
    const __half* __restrict__ sx_u, const __half* __restrict__ sx_i,
    float* __restrict__ out_user, float* __restrict__ out_item,
    int N_ITEM, int NT)
{
    int wid = (blockIdx.x * 256 + threadIdx.x) >> 6;
    int lane = threadIdx.x & 63;
    if (wid >= NT) return;
    const bool is_item_tgt = (wid < N_ITEM);
    const __half* sfeat = is_item_tgt ? sx_u : sx_i;   // sources are the other side
    float* orow = is_item_tgt ? &out_item[(size_t)wid * 64]
                              : &out_user[(size_t)(wid - N_ITEM) * 64];
    int end = ofs[wid];
    int deg = cnt[wid];
    int start = end - deg;
    float msg0 = 0.f, msg1 = 0.f, den = 0.f;
    for (int base = start; base < end; base += 64) {
        int nk = end - base; if (nk > 64) nk = 64;
        int2 p = make_int2(0, 0);
        if (base + lane < end) p = payload[base + lane];
        int k = 0;
        for (; k + 1 < nk; k += 2) {
            int  sA = __shfl(p.x, k);
            int  sB = __shfl(p.x, k + 1);
            float aA = __int_as_float(__shfl(p.y, k));
            float aB = __int_as_float(__shfl(p.y, k + 1));
            float fA = __half2float(sfeat[(size_t)sA * 64 + lane]);
            float fB = __half2float(sfeat[(size_t)sB * 64 + lane]);
            msg0 += aA * fA;
            msg1 += aB * fB;
            den += aA + aB;
        }
        if (k < nk) {
            int  sA = __shfl(p.x, k);
            float aA = __int_as_float(__shfl(p.y, k));
            msg0 += aA * __half2float(sfeat[(size_t)sA * 64 + lane]);
            den += aA;
        }
    }
    orow[lane] += (msg0 + msg1) / (den + EPS);
}

extern "C" void kernel_launch(void* const* d_in, const int* in_sizes, int n_in,
                              void* d_out, int out_size, void* d_ws, size_t ws_size,
                              hipStream_t stream) {
    const float* x_user   = (const float*)d_in[0];
    const float* x_item   = (const float*)d_in[1];
    const float* W_ui_src = (const float*)d_in[2];
    const float* W_ui_tgt = (const float*)d_in[3];
    const float* W_iu_src = (const float*)d_in[4];
    const float* W_iu_tgt = (const float*)d_in[5];
    const float* a_ui     = (const float*)d_in[6];   // [128]
    const float* a_iu     = (const float*)d_in[7];   // [128]
    const int*   edge_ui  = (const int*)d_in[8];     // [2][E]
    const int*   edge_iu  = (const int*)d_in[9];

    const int N_USER = in_sizes[0] / D_IN;
    const int N_ITEM = in_sizes[1] / D_IN;
    const int E_ui = in_sizes[8] / 2;
    const int E_iu = in_sizes[9] / 2;
    const int NMAX = (N_USER > N_ITEM) ? N_USER : N_ITEM;
    const int NT = N_ITEM + N_USER;       // combined target domain (items first)
    const int ET = E_ui + E_iu;

    float* out = (float*)d_out;
    float* out_user = out;                          // [N_USER][64]
    float* out_item = out + (size_t)N_USER * 64;    // [N_ITEM][64]

    // ---- workspace layout ----
    float* w = (float*)d_ws;
    __half* sx_u = (__half*)w;  w += (size_t)NMAX * 32;   // N*64 halves
    __half* sx_i = (__half*)w;  w += (size_t)NMAX * 32;
    float* s_src_ui = w;  w += N_USER;
    float* t_tgt_iu = w;  w += N_USER;
    float* s_src_iu = w;  w += N_ITEM;
    float* t_tgt_ui = w;  w += N_ITEM;
    int* cnt  = (int*)w;  w += NT;
    int* ofs  = (int*)w;  w += NT;
    int nb_scan = (NT + 255) / 256;
    int* bsum = (int*)w;  w += (nb_scan + 2) & ~1;   // keep 8B alignment
    int2* payload = (int2*)w;  w += (size_t)2 * ET;

    size_t need_bytes = (size_t)(w - (float*)d_ws) * sizeof(float);
    if (ws_size < need_bytes) return;  // clean, diagnosable failure

    int nb_u = (N_USER + 63) / 64;
    int nb_i = (N_ITEM + 63) / 64;

    // 1. both GEMMs in one dispatch
    gemm_score_dual<<<nb_u + nb_i, 256, 0, stream>>>(
        x_user, x_item, W_ui_src, W_ui_tgt, W_iu_src, W_iu_tgt, a_ui, a_iu,
        sx_u, sx_i, out_user, out_item,
        s_src_ui, t_tgt_iu, s_src_iu, t_tgt_ui,
        nb_u, N_USER, N_ITEM);

    // 2. combined CSR build over both edge types
    hipMemsetAsync(cnt, 0, (size_t)NT * sizeof(int), stream);
    hist_kernel<<<(ET + 255) / 256, 256, 0, stream>>>(
        edge_ui + E_ui, edge_iu + E_iu, cnt, E_ui, E_iu, N_ITEM);
    scan_block<<<nb_scan, 256, 0, stream>>>(cnt, ofs, bsum, NT);
    scan_bsums<<<1, 256, 0, stream>>>(bsum, nb_scan);
    add_offsets<<<nb_scan, 256, 0, stream>>>(ofs, bsum, NT);
    fill_kernel<<<(ET + 255) / 256, 256, 0, stream>>>(
        edge_ui, edge_iu, s_src_ui, t_tgt_ui, s_src_iu, t_tgt_iu,
        ofs, payload, E_ui, E_iu, N_ITEM);

    // 3. combined gather + finalize
    gather_out<<<((size_t)NT * 64 + 255) / 256, 256, 0, stream>>>(
        payload, ofs, cnt, sx_u, sx_i, out_user, out_item, N_ITEM, NT);
}